// Round 5
// baseline (411.247 us; speedup 1.0000x reference)
//
#include <hip/hip_runtime.h>
#include <hip/hip_bf16.h>

#define N_NODES 50000
#define N_EDGES 800000
#define DIM 64
#define NB 391      // dst buckets of 128 nodes: ceil(50000/128)
#define NBLK 128    // blocks in bucketize pass
#define CHUNK 6250  // N_EDGES / NBLK (exact)
#define CAP 4096    // LDS staging capacity per bucket segment (avg ~2048)
#define NTILES 3125 // 50000 / 16 row-tiles (exact)

typedef __attribute__((ext_vector_type(8))) short bf16x8;
typedef __attribute__((ext_vector_type(4))) float f32x4;

// ---------- helpers ----------
__device__ __forceinline__ float bf2f(unsigned short u) {
  return __uint_as_float(((unsigned int)u) << 16);
}
__device__ __forceinline__ unsigned short f2bf(float f) {
  unsigned int x = __float_as_uint(f);
  unsigned int r = (x + 0x7fffu + ((x >> 16) & 1u)) >> 16;  // RNE
  return (unsigned short)r;
}

// ---------- dtype detection (flags[0]=bf16 inputs, flags[1]=int64 indices) ----------
__global__ void k_detect(const unsigned short* __restrict__ feat,
                         const unsigned int* __restrict__ eidx,
                         int* __restrict__ flags) {
  int lane = threadIdx.x;  // 64 threads
  float v = bf2f(feat[2 * lane]);
  bool big = !(fabsf(v) < 1000.0f);
  unsigned long long bb = __ballot(big);
  unsigned int w = eidx[2 * lane + 1];
  unsigned long long bz = __ballot(w == 0u);
  if (lane == 0) {
    flags[0] = (__popcll(bb) < 8) ? 1 : 0;
    flags[1] = (__popcll(bz) == 64) ? 1 : 0;
  }
}

__device__ __forceinline__ int eidx_at(const int* __restrict__ p, int k, int i64) {
  return p[i64 ? (k << 1) : k];
}

// ---------- one-time fragment prep (R12) ----------
// Per head-matrix b (0..7): swizzle W into bf16 hi/lo MFMA B-fragments
// (vector-loadable: 16 B per lane per (cb,ks)), and precompute
// was = W@a_s, wad = W@a_d in fp32, stored as a hi/lo B-fragment with
// cols {0:was_hi, 1:was_lo, 2:wad_hi, 3:wad_lo, 4-15:0}. This removes the
// per-wave 64-scalar-load + ~400-VALU W preamble and turns the score
// reduction (was 32 ds_bpermutes) into 4 MFMAs + 4 shuffles in k_gemm.
__global__ __launch_bounds__(256) void k_wprep(
    const void* __restrict__ W1, const void* __restrict__ A1s,
    const void* __restrict__ A1d, const void* __restrict__ W2,
    const void* __restrict__ A2s, const void* __restrict__ A2d,
    const int* __restrict__ flags, unsigned short* __restrict__ wfH,
    unsigned short* __restrict__ wfL, unsigned short* __restrict__ baf) {
  __shared__ float Wsh[DIM * DIM];
  __shared__ float was[DIM], wad[DIM];
  const int b = blockIdx.x;  // head-matrix 0..7
  const int t = threadIdx.x;
  const int bf = flags[0];
  const void* Wv = (b < 4) ? W1 : W2;
  const void* av = (b < 4) ? A1s : A2s;
  const void* dv = (b < 4) ? A1d : A2d;
  const int hm = (b < 4) ? b : b - 4;
  for (int i = t; i < DIM * DIM; i += 256)
    Wsh[i] = bf ? bf2f(((const unsigned short*)Wv)[hm * DIM * DIM + i])
                : ((const float*)Wv)[hm * DIM * DIM + i];
  __syncthreads();
  if (t < 128) {
    int k = t & 63, isd = t >> 6;
    const void* aptr = isd ? dv : av;
    float acc = 0.f;
    for (int c = 0; c < DIM; ++c) {
      float a = bf ? bf2f(((const unsigned short*)aptr)[hm * DIM + c])
                   : ((const float*)aptr)[hm * DIM + c];
      acc = fmaf(Wsh[k * DIM + c], a, acc);
    }
    (isd ? wad : was)[k] = acc;
  }
  __syncthreads();
  // W fragments: value at (cb,ks,lane,j) = W[(32ks+8g4+j)*64 + 16cb+r16]
  for (int idx = t; idx < 512; idx += 256) {
    int lane = idx & 63, ks = (idx >> 6) & 1, cb = idx >> 7;
    int g4 = lane >> 4, r16 = lane & 15;
    int fo = (((b * 4 + cb) * 2 + ks) * 64 + lane) * 8;
#pragma unroll
    for (int j = 0; j < 8; ++j) {
      int k = 32 * ks + 8 * g4 + j;
      float w = Wsh[k * DIM + 16 * cb + r16];
      unsigned short hu = f2bf(w);
      wfH[fo + j] = hu;
      wfL[fo + j] = f2bf(w - bf2f(hu));
    }
  }
  // score fragments
  for (int idx = t; idx < 128; idx += 256) {
    int lane = idx & 63, ks = idx >> 6;
    int g4 = lane >> 4, r16 = lane & 15;
    int fo = ((b * 2 + ks) * 64 + lane) * 8;
#pragma unroll
    for (int j = 0; j < 8; ++j) {
      int k = 32 * ks + 8 * g4 + j;
      unsigned short u = 0;
      if (r16 < 4) {
        float w_ = (r16 < 2) ? was[k] : wad[k];
        unsigned short uh = f2bf(w_);
        u = (r16 & 1) ? f2bf(w_ - bf2f(uh)) : uh;
      }
      baf[fo + j] = u;
    }
  }
}

// ---------- layer-0 feature split: x -> hi/lo bf16 ----------
__global__ __launch_bounds__(256) void k_split(const void* __restrict__ feat,
                                               const int* __restrict__ flags,
                                               unsigned short* __restrict__ xh,
                                               unsigned short* __restrict__ xl) {
  int i = (blockIdx.x * 256 + threadIdx.x) * 4;
  if (i >= N_NODES * DIM) return;
  if (flags[0]) {
    ushort4 v = *(const ushort4*)((const unsigned short*)feat + i);
    *(ushort4*)(xh + i) = v;
    *(ushort4*)(xl + i) = make_ushort4(0, 0, 0, 0);
  } else {
    float4 f = *(const float4*)((const float*)feat + i);
    ushort4 h4, l4;
    h4.x = f2bf(f.x); l4.x = f2bf(f.x - bf2f(h4.x));
    h4.y = f2bf(f.y); l4.y = f2bf(f.y - bf2f(h4.y));
    h4.z = f2bf(f.z); l4.z = f2bf(f.z - bf2f(h4.z));
    h4.w = f2bf(f.w); l4.w = f2bf(f.w - bf2f(h4.w));
    *(ushort4*)(xh + i) = h4;
    *(ushort4*)(xl + i) = l4;
  }
}

// ---------- generalized scan (n <= 65536) ----------
__global__ void k_scan1(const int* __restrict__ in, int* __restrict__ out,
                        int* __restrict__ bsum, int n) {
  __shared__ int sm[256];
  int t = threadIdx.x, b = blockIdx.x, i = b * 256 + t;
  int v = (i < n) ? in[i] : 0;
  sm[t] = v;
  __syncthreads();
  for (int off = 1; off < 256; off <<= 1) {
    int x = (t >= off) ? sm[t - off] : 0;
    __syncthreads();
    sm[t] += x;
    __syncthreads();
  }
  if (i < n) out[i] = sm[t] - v;
  if (t == 255) bsum[b] = sm[t];
}

__global__ void k_scan2(int* __restrict__ bsum, int nb) {
  __shared__ int sm[256];
  int t = threadIdx.x;
  int v = (t < nb) ? bsum[t] : 0;
  sm[t] = v;
  __syncthreads();
  for (int off = 1; off < 256; off <<= 1) {
    int x = (t >= off) ? sm[t - off] : 0;
    __syncthreads();
    sm[t] += x;
    __syncthreads();
  }
  if (t < nb) bsum[t] = sm[t] - v;
}

__global__ void k_scan3(int* __restrict__ out, const int* __restrict__ bsum, int n) {
  int t = threadIdx.x, b = blockIdx.x, i = b * 256 + t;
  if (i < n) out[i] += bsum[b];
}

// ---------- bucketed CSR build ----------
__global__ __launch_bounds__(256) void k_hist1(const int* __restrict__ eidx,
                                               const int* __restrict__ flags,
                                               int* __restrict__ hist) {
  __shared__ int h[NB];
  int t = threadIdx.x, b = blockIdx.x;
  for (int i = t; i < NB; i += 256) h[i] = 0;
  __syncthreads();
  int i64 = flags[1];
  int lo = b * CHUNK;
  for (int i = t; i < CHUNK; i += 256) {
    int d = eidx_at(eidx, N_EDGES + lo + i, i64);
    atomicAdd(&h[d >> 7], 1);
  }
  __syncthreads();
  for (int i = t; i < NB; i += 256) hist[i * NBLK + b] = h[i];
}

__global__ __launch_bounds__(256) void k_scatter(const int* __restrict__ eidx,
                                                 const int* __restrict__ flags,
                                                 const int* __restrict__ hscan,
                                                 int2* __restrict__ ebuf) {
  __shared__ int cur[NB];
  int t = threadIdx.x, b = blockIdx.x;
  for (int i = t; i < NB; i += 256) cur[i] = hscan[i * NBLK + b];
  __syncthreads();
  int i64 = flags[1];
  int lo = b * CHUNK;
  for (int i = t; i < CHUNK; i += 256) {
    int d = eidx_at(eidx, N_EDGES + lo + i, i64);
    int s = eidx_at(eidx, lo + i, i64);
    int pos = atomicAdd(&cur[d >> 7], 1);
    ebuf[pos] = make_int2(s, d);
  }
}

// fused: per-bucket degree histogram + local scan -> rowp, then LDS-staged
// CSR placement (bucket segments are dst-contiguous).
__global__ __launch_bounds__(256) void k_place(const int2* __restrict__ ebuf,
                                               const int* __restrict__ hscan,
                                               int* __restrict__ rowp,
                                               int* __restrict__ csr) {
  __shared__ int hcnt[128];
  __shared__ int sm[128];
  __shared__ int cur[128];
  __shared__ int lcsr[CAP];
  int t = threadIdx.x, b = blockIdx.x;
  int lo = hscan[b * NBLK];
  int hi = (b + 1 < NB) ? hscan[(b + 1) * NBLK] : N_EDGES;
  if (t < 128) hcnt[t] = 0;
  __syncthreads();
  for (int i = lo + t; i < hi; i += 256) atomicAdd(&hcnt[ebuf[i].y & 127], 1);
  __syncthreads();
  int v = (t < 128) ? hcnt[t] : 0;
  if (t < 128) sm[t] = v;
  __syncthreads();
  for (int off = 1; off < 128; off <<= 1) {
    int x = (t < 128 && t >= off) ? sm[t - off] : 0;
    __syncthreads();
    if (t < 128) sm[t] += x;
    __syncthreads();
  }
  int d0 = b * 128;
  if (t < 128) {
    int excl = sm[t] - v;  // exclusive local prefix
    cur[t] = excl;
    int d = d0 + t;
    if (d < N_NODES) rowp[d] = lo + excl;
  }
  if (b == NB - 1 && t == 0) rowp[N_NODES] = N_EDGES;
  __syncthreads();
  int seg_sz = hi - lo;
  if (seg_sz <= CAP) {
    for (int i = lo + t; i < hi; i += 256) {
      int2 pr = ebuf[i];
      int pos = atomicAdd(&cur[pr.y & 127], 1);
      lcsr[pos] = pr.x;
    }
    __syncthreads();
    for (int i = t; i < seg_sz; i += 256) csr[lo + i] = lcsr[i];
  } else {  // overflow fallback
    for (int i = lo + t; i < hi; i += 256) {
      int2 pr = ebuf[i];
      int pos = atomicAdd(&cur[pr.y & 127], 1);
      csr[lo + pos] = pr.x;
    }
  }
}

// ---------- MFMA h = x@W (R12: pure-load wave, pre-swizzled fragments) ----------
// Per wave: half a 16-row tile (2 of 4 col-blocks) -> 6250 waves, ~90 VGPR,
// ~5 waves/SIMD. All operands are preconverted bf16 hi/lo: A from xh/xl
// (k_split / k_agg), B from wfH/wfL, scores via 4 MFMAs against baf
// (cols 0/1 = was hi/lo, 2/3 = wad hi/lo) + one shfl_xor(.,1) pair-sum.
// D layout (m89-verified): col = lane&15, row = (lane>>4)*4 + reg.
// 3-term product (AhBh + AlBh + AhBl); for bf16 inputs the lo buffers are
// zero so the extra terms are harmless no-ops.
__global__ __launch_bounds__(256) void k_gemm(
    const unsigned short* __restrict__ xh, const unsigned short* __restrict__ xl,
    const unsigned short* __restrict__ wfH, const unsigned short* __restrict__ wfL,
    const unsigned short* __restrict__ baf, int mat,
    unsigned short* __restrict__ hb, float* __restrict__ ss,
    float* __restrict__ sd) {
  const int lane = threadIdx.x & 63;
  const int w = blockIdx.x * 4 + (threadIdx.x >> 6);
  const int wtile = w >> 1;
  if (wtile >= NTILES) return;
  const int cbh = (w & 1) * 2;  // col-blocks {cbh, cbh+1}
  const int r16 = lane & 15;
  const int g4 = lane >> 4;
  const int row0 = wtile * 16;

  const bf16x8* WH = (const bf16x8*)wfH;
  const bf16x8* WL = (const bf16x8*)wfL;
  bf16x8 Bh[2][2], Bl[2][2];
#pragma unroll
  for (int c = 0; c < 2; ++c)
#pragma unroll
    for (int ks = 0; ks < 2; ++ks) {
      int fi = ((mat * 4 + cbh + c) * 2 + ks) * 64 + lane;
      Bh[c][ks] = WH[fi];
      Bl[c][ks] = WL[fi];
    }

  bf16x8 Ah[2], Al[2];
#pragma unroll
  for (int ks = 0; ks < 2; ++ks) {
    Ah[ks] = *(const bf16x8*)(xh + (row0 + r16) * DIM + 32 * ks + 8 * g4);
    Al[ks] = *(const bf16x8*)(xl + (row0 + r16) * DIM + 32 * ks + 8 * g4);
  }

  f32x4 acc[2];
#pragma unroll
  for (int c = 0; c < 2; ++c) {
    acc[c] = (f32x4){0.f, 0.f, 0.f, 0.f};
#pragma unroll
    for (int ks = 0; ks < 2; ++ks) {
      acc[c] = __builtin_amdgcn_mfma_f32_16x16x32_bf16(Ah[ks], Bh[c][ks], acc[c], 0, 0, 0);
      acc[c] = __builtin_amdgcn_mfma_f32_16x16x32_bf16(Al[ks], Bh[c][ks], acc[c], 0, 0, 0);
      acc[c] = __builtin_amdgcn_mfma_f32_16x16x32_bf16(Ah[ks], Bl[c][ks], acc[c], 0, 0, 0);
    }
  }

  // h store (bf16)
#pragma unroll
  for (int c = 0; c < 2; ++c)
#pragma unroll
    for (int reg = 0; reg < 4; ++reg)
      hb[(row0 + 4 * g4 + reg) * DIM + (cbh + c) * 16 + r16] = f2bf(acc[c][reg]);

  // scores: only the cbh==0 wave of each tile
  if (cbh == 0) {
    f32x4 acc2 = (f32x4){0.f, 0.f, 0.f, 0.f};
#pragma unroll
    for (int ks = 0; ks < 2; ++ks) {
      bf16x8 Ba = *(const bf16x8*)(baf + ((mat * 2 + ks) * 64 + lane) * 8);
      acc2 = __builtin_amdgcn_mfma_f32_16x16x32_bf16(Ah[ks], Ba, acc2, 0, 0, 0);
      acc2 = __builtin_amdgcn_mfma_f32_16x16x32_bf16(Al[ks], Ba, acc2, 0, 0, 0);
    }
#pragma unroll
    for (int reg = 0; reg < 4; ++reg) {
      float tmp = acc2[reg] + __shfl_xor(acc2[reg], 1);  // col pairs (0,1)/(2,3)
      int row = row0 + 4 * g4 + reg;
      if (r16 == 0) ss[row] = tmp;
      else if (r16 == 2) sd[row] = tmp;
    }
  }
}

// ---------- per-dst-node softmax aggregation (one wave per node, R6/R8 proven) ----------
// quad-gather: quarter-wave (16 lanes) per edge, each lane loads ushort4
// (4 cols, 8 B) -> one full 128 B h-row per quarter-wave, 4 edges & 512 B
// per load instruction. Softmax without max-subtraction (shift-invariant;
// scores are O(10) so fp32 exp is safe — verified bit-identical absmax in R9).
// R12: non-final output written as hi/lo bf16 pair (same split arithmetic
// k_gemm used to do per-wave — moved here, done once).
__device__ __forceinline__ void quad_accum(const unsigned short* __restrict__ hb,
                                           const int2* __restrict__ lps, int cl,
                                           int quarter, int c16, float4& acc) {
  const int quads = (cl + 3) >> 2;
#pragma unroll 4
  for (int tt = 0; tt < quads; ++tt) {
    int j = 4 * tt + quarter;  // tail entries have p=0,s=0 -> contribute 0
    int2 pv = lps[j];          // LDS broadcast within quarter-wave
    float pj = __int_as_float(pv.x);
    int sj = pv.y;
    ushort4 hv = *(const ushort4*)(hb + sj * DIM + 4 * c16);
    acc.x = fmaf(pj, bf2f(hv.x), acc.x);
    acc.y = fmaf(pj, bf2f(hv.y), acc.y);
    acc.z = fmaf(pj, bf2f(hv.z), acc.z);
    acc.w = fmaf(pj, bf2f(hv.w), acc.w);
  }
}

__global__ __launch_bounds__(256) void k_agg(
    const unsigned short* __restrict__ hb, const float* __restrict__ ss,
    const float* __restrict__ sd, const int* __restrict__ rowp,
    const int* __restrict__ csr, unsigned short* __restrict__ outH,
    unsigned short* __restrict__ outL, void* __restrict__ out_final,
    const int* __restrict__ flags, int do_elu, int is_final) {
  __shared__ __align__(16) int2 lps[4][64];  // {p bits, src}
  const int lane = threadIdx.x & 63;
  const int quarter = lane >> 4;
  const int c16 = lane & 15;  // this lane covers cols 4*c16 .. 4*c16+3
  const int w = threadIdx.x >> 6;
  const int node = blockIdx.x * 4 + w;
  const int base = rowp[node];
  const int deg = rowp[node + 1] - base;
  const float sdn = sd[node];

  float4 acc = {0.f, 0.f, 0.f, 0.f};
  float z;
  if (deg <= 64) {
    int s = 0;
    float p = 0.f;
    if (lane < deg) {
      s = csr[base + lane];
      float t = ss[s] + sdn;
      t = (t >= 0.f) ? t : 0.2f * t;
      p = __expf(t);  // no max-subtraction needed (shift-invariant, scores O(10))
    }
    lps[w][lane] = make_int2(__float_as_int(p), s);
    z = p;
    __builtin_amdgcn_wave_barrier();
    quad_accum(hb, &lps[w][0], deg, quarter, c16, acc);
    // z-reduce after the gathers are issued; overlaps with acc combine below
#pragma unroll
    for (int off = 32; off > 0; off >>= 1) z += __shfl_xor(z, off);
  } else {
    z = 0.f;
    for (int c = 0; c < deg; c += 64) {
      int j = c + lane;
      float p = 0.f; int s = 0;
      if (j < deg) {
        s = csr[base + j];
        float sc = ss[s] + sdn;
        sc = (sc >= 0.f) ? sc : 0.2f * sc;
        p = __expf(sc);
      }
      lps[w][lane] = make_int2(__float_as_int(p), s);
      __builtin_amdgcn_wave_barrier();
      z += p;
      const int cl = (deg - c < 64) ? (deg - c) : 64;
      quad_accum(hb, &lps[w][0], cl, quarter, c16, acc);
      __builtin_amdgcn_wave_barrier();
    }
#pragma unroll
    for (int off = 32; off > 0; off >>= 1) z += __shfl_xor(z, off);
  }

  // combine the four quarter-wave partial sums (same cols, disjoint edges)
  acc.x += __shfl_xor(acc.x, 16);
  acc.y += __shfl_xor(acc.y, 16);
  acc.z += __shfl_xor(acc.z, 16);
  acc.w += __shfl_xor(acc.w, 16);
  acc.x += __shfl_xor(acc.x, 32);
  acc.y += __shfl_xor(acc.y, 32);
  acc.z += __shfl_xor(acc.z, 32);
  acc.w += __shfl_xor(acc.w, 32);

  float inv = 1.f / (z + 1e-16f);  // deg==0 -> 0, matches reference
  float ox = acc.x * inv, oy = acc.y * inv;
  float oz = acc.z * inv, ow = acc.w * inv;
  if (do_elu) {
    ox = (ox > 0.f) ? ox : expm1f(ox);
    oy = (oy > 0.f) ? oy : expm1f(oy);
    oz = (oz > 0.f) ? oz : expm1f(oz);
    ow = (ow > 0.f) ? ow : expm1f(ow);
  }
  if (quarter == 0) {
    int idx = node * DIM + 4 * c16;
    if (is_final) {
      if (flags[0]) {
        ushort4 o4 = {f2bf(ox), f2bf(oy), f2bf(oz), f2bf(ow)};
        *(ushort4*)((unsigned short*)out_final + idx) = o4;
      } else {
        float4 o4 = {ox, oy, oz, ow};
        *(float4*)((float*)out_final + idx) = o4;
      }
    } else {
      ushort4 h4, l4;
      h4.x = f2bf(ox); l4.x = f2bf(ox - bf2f(h4.x));
      h4.y = f2bf(oy); l4.y = f2bf(oy - bf2f(h4.y));
      h4.z = f2bf(oz); l4.z = f2bf(oz - bf2f(h4.z));
      h4.w = f2bf(ow); l4.w = f2bf(ow - bf2f(h4.w));
      *(ushort4*)(outH + idx) = h4;
      *(ushort4*)(outL + idx) = l4;
    }
  }
}

// ---------- launch ----------
extern "C" void kernel_launch(void* const* d_in, const int* in_sizes, int n_in,
                              void* d_out, int out_size, void* d_ws, size_t ws_size,
                              hipStream_t stream) {
  const void* feat = d_in[0];
  const int* eidx = (const int*)d_in[1];

  unsigned short* xh0 = (unsigned short*)d_ws;          // N*64 bf16 (hi, buf0)
  unsigned short* xl0 = xh0 + N_NODES * DIM;            // N*64 bf16 (lo, buf0)
  unsigned short* xh1 = xl0 + N_NODES * DIM;            // N*64 bf16 (hi, buf1)
  unsigned short* xl1 = xh1 + N_NODES * DIM;            // N*64 bf16 (lo, buf1)
  unsigned short* hb  = xl1 + N_NODES * DIM;            // N*64 bf16
  unsigned short* wfH = hb + N_NODES * DIM;             // 8*4*2*64*8 = 32768
  unsigned short* wfL = wfH + 32768;                    // 32768
  unsigned short* baf = wfL + 32768;                    // 8*2*64*8 = 8192
  int2* ebuf = (int2*)(baf + 8192);                     // E int2
  float* ssrc = (float*)(ebuf + N_EDGES);               // N
  float* sdst = ssrc + N_NODES;                         // N
  int* csr  = (int*)(sdst + N_NODES);                   // E
  int* hist = csr + N_EDGES;                            // NB*NBLK
  int* hscan = hist + NB * NBLK;                        // NB*NBLK
  int* bsum = hscan + NB * NBLK;                        // 256
  int* rowp = bsum + 256;                               // N+1
  int* flags = rowp + N_NODES + 1;                      // 2

  const int NH = NB * NBLK;                 // 50048
  const int SBH = (NH + 255) / 256;         // 196

  k_detect<<<1, 64, 0, stream>>>((const unsigned short*)feat,
                                 (const unsigned int*)eidx, flags);
  k_wprep<<<8, 256, 0, stream>>>(d_in[2], d_in[3], d_in[4],
                                 d_in[5], d_in[6], d_in[7],
                                 flags, wfH, wfL, baf);
  k_split<<<(N_NODES * DIM / 4 + 255) / 256, 256, 0, stream>>>(feat, flags, xh1, xl1);
  k_hist1<<<NBLK, 256, 0, stream>>>(eidx, flags, hist);
  k_scan1<<<SBH, 256, 0, stream>>>(hist, hscan, bsum, NH);
  k_scan2<<<1, 256, 0, stream>>>(bsum, SBH);
  k_scan3<<<SBH, 256, 0, stream>>>(hscan, bsum, NH);
  k_scatter<<<NBLK, 256, 0, stream>>>(eidx, flags, hscan, ebuf);
  k_place<<<NB, 256, 0, stream>>>(ebuf, hscan, rowp, csr);

  const int GB = (2 * NTILES + 3) / 4;  // 6250 waves, 2 waves/tile

  const unsigned short* xh = xh1;
  const unsigned short* xl = xl1;
  for (int i = 0; i < 8; ++i) {
    k_gemm<<<GB, 256, 0, stream>>>(xh, xl, wfH, wfL, baf, i, hb, ssrc, sdst);
    int elu = (i == 3 || i == 7) ? 1 : 0;
    int fin = (i == 7) ? 1 : 0;
    unsigned short* oh = (i & 1) ? xh1 : xh0;
    unsigned short* ol = (i & 1) ? xl1 : xl0;
    k_agg<<<N_NODES / 4, 256, 0, stream>>>(hb, ssrc, sdst, rowp, csr, oh, ol,
                                           d_out, flags, elu, fin);
    xh = oh; xl = ol;
  }
}